// Round 7
// baseline (166.861 us; speedup 1.0000x reference)
//
#include <hip/hip_runtime.h>
#include <math.h>

// Problem constants (fixed by setup_inputs)
#define BATCH 32768
#define SS 16          // bands / sequence
#define DI 14          // input dim
#define BQ 256         // stored patterns
#define NC 7           // classes
#define NBLK 2048      // 4 waves/block -> 8192 waves, 4 contiguous batches/wave

// ws layout:
//   mpack : double2[7][256]  (28672 B) m-tilde = g_sp*k - (S/14), packed dim-pairs x pattern
//   Tf    : float[256*7]     ( 7168 B) per-pattern class contribution table
//   zb    : double[7]        (   56 B) bm[c]*sum(Wb) + bb
//   cvec  : double[256]      ( 2048 B) c_j = b_sp . k_j   (all 0 for these inputs)
//   hc    : int              (    4 B) any(b_sp != 0)
#define WS_MPACK_OFF 0
#define WS_TF_OFF    28672
#define WS_ZB_OFF    35840
#define WS_CV_OFF    35896
#define WS_HC_OFF    37944

typedef float  f32x16 __attribute__((ext_vector_type(16)));
typedef short  s16x8  __attribute__((ext_vector_type(8)));
typedef float  v2f    __attribute__((ext_vector_type(2)));

__device__ __forceinline__ unsigned short bf16_rne(float f) {
    unsigned u = __float_as_uint(f);
    unsigned r = u + 0x7FFFu + ((u >> 16) & 1u);
    return (unsigned short)(r >> 16);
}
__device__ __forceinline__ float bf16_to_f32(unsigned short h) {
    return __uint_as_float(((unsigned)h) << 16);
}

// Monotone fp32->u32 order map, top 24 bits kept, low byte = (255-j).
// u32 compare == "score desc, then lowest j" at 2^-16 relative quantization —
// below the bf16-split scan error; fp64 rescore covers both error tiers.
__device__ __forceinline__ unsigned key32(float v, int j) {
    unsigned u = __float_as_uint(v);
    u ^= ((unsigned)((int)u >> 31)) | 0x80000000u;
    return (u & 0xFFFFFF00u) | (unsigned)(255 - j);
}

__global__ __launch_bounds__(256) void precompute_kernel(
    const float* __restrict__ lookup,
    const float* __restrict__ g_st, const float* __restrict__ b_st,
    const float* __restrict__ g_pp, const float* __restrict__ b_pp,
    const float* __restrict__ g_sp, const float* __restrict__ b_sp,
    const float* __restrict__ Wv,  const float* __restrict__ Wo,
    const float* __restrict__ Wm,  const float* __restrict__ bm,
    const float* __restrict__ Wb,  const float* __restrict__ bb,
    double2* __restrict__ mpack, float* __restrict__ Tf, double* __restrict__ zb,
    double* __restrict__ cvec, int* __restrict__ hc)
{
    __shared__ double G1s[256][7];   // (Wo.T @ Wm.T)  : [p][c]
    __shared__ double Gs[14][7];     // Wv.T @ G1      : [d][c]
    const int tid = threadIdx.x;

    // G1[p][c] = sum_o Wo[o,p] * Wm[c,o]
    {
        const int p = tid;
        for (int c = 0; c < NC; ++c) {
            double acc = 0.0;
            for (int o = 0; o < 28; ++o)
                acc += (double)Wo[o * 256 + p] * (double)Wm[c * 28 + o];
            G1s[p][c] = acc;
        }
    }
    __syncthreads();
    // G[d][c] = sum_p Wv[p,d] * G1[p][c]
    if (tid < DI * NC) {
        const int d = tid / NC, c = tid % NC;
        double acc = 0.0;
        for (int p = 0; p < 256; ++p)
            acc += (double)Wv[p * DI + d] * G1s[p][c];
        Gs[d][c] = acc;
    }
    __syncthreads();

    // Per stored pattern j: LayerNorm once (fp64), emit m-tilde, c_j, T row.
    {
        const int j = tid;
        double xr[DI];
        double sum = 0.0;
        for (int d = 0; d < DI; ++d) { xr[d] = (double)lookup[j * DI + d]; sum += xr[d]; }
        const double mu = sum * (1.0 / (double)DI);
        double vs = 0.0;
        for (int d = 0; d < DI; ++d) { const double t = xr[d] - mu; vs += t * t; }
        const double rs = 1.0 / sqrt(vs * (1.0 / (double)DI) + 1e-5);

        double kj[DI], vl[DI];
        for (int d = 0; d < DI; ++d) {
            const double nrm = (xr[d] - mu) * rs;
            kj[d] = nrm * (double)g_st[d] + (double)b_st[d];
            vl[d] = nrm * (double)g_pp[d] + (double)b_pp[d];
        }
        // m_j = g_sp .* k_j ; m~_j = m_j - (sum m_j)/14 ; c_j = b_sp . k_j
        double mv[DI], S = 0.0, cj = 0.0;
        for (int d = 0; d < DI; ++d) {
            mv[d] = kj[d] * (double)g_sp[d];
            S += mv[d];
            cj += (double)b_sp[d] * kj[d];
        }
        const double Sm = S * (1.0 / (double)DI);
        for (int d2 = 0; d2 < DI / 2; ++d2) {
            double2 p; p.x = mv[2 * d2] - Sm; p.y = mv[2 * d2 + 1] - Sm;
            mpack[d2 * 256 + j] = p;
        }
        cvec[j] = cj;

        for (int c = 0; c < NC; ++c) {
            double acc = 0.0;
            for (int d = 0; d < DI; ++d) acc += vl[d] * Gs[d][c];
            Tf[j * NC + c] = (float)acc;
        }
    }
    if (tid < NC) {
        double wbsum = 0.0;
        for (int s = 0; s < SS; ++s) wbsum += (double)Wb[s];
        zb[tid] = (double)bm[tid] * wbsum + (double)bb[0];
    }
    if (tid == 0) {
        int f = 0;
        for (int d = 0; d < DI; ++d) f |= (b_sp[d] != 0.0f) ? 1 : 0;
        *hc = f;
    }
}

// One wave = 4 contiguous batches processed as 2 PAIRS via 32x32x16 MFMA:
// tile = 32 patterns x 32 cols (2 batches x 16 bands), K=16 (DI=14 + irs dim,
// NO padding waste). A = pattern frags (row=lane&31, k=(lane>>5)*8+i),
// B = x frags (col=lane&31, k=(lane>>5)*8+i). C (m74/m101-verified):
// col=lane&31=(batchInPair,band), row=(reg&3)+8*(reg>>2)+4*(lane>>5).
// Per lane: 16 per-reg trackers; cells {j = c mod 32} of size 8 — the exact
// partition proven in R6. In-lane top-2 tree + one lane^32 shfl merge.
// fp64 rescore of top-2 per band unchanged -> identical decisions.
__global__ __launch_bounds__(256, 4) void hopfield_kernel(
    const float* __restrict__ x,
    const double2* __restrict__ mpack, const double* __restrict__ cvec,
    const int* __restrict__ hcp,
    const float* __restrict__ Tf, const double* __restrict__ zb,
    const float* __restrict__ Wb, float* __restrict__ out)
{
    __shared__ s16x8  bhiS[8 * 64];           // pattern hi frags [tile][lane]  8 KiB
    __shared__ s16x8  bloS[8 * 64];           // pattern lo frags               8 KiB
    __shared__ double zbs[NC];
    __shared__ float  wbs[SS];
    __shared__ int    jcandS[4][4][SS][2];    // [wave][bi][band][cand]
    __shared__ int    jstarS[4][4][SS];
    __shared__ double zrowd[4][4][NC];
    __shared__ float  irsS[4][4][SS];         // general path only (hc != 0)

    const int tid  = threadIdx.x;
    const int lane = tid & 63;
    const int w    = tid >> 6;
    const int hc   = *hcp;

    // ---- stage pattern fragments (hi/lo bf16 splits of fp32(m~)), thread = pattern j ----
    // entry index for (j, khalf): (j>>5)*64 + khalf*32 + (j&31); k = khalf*8 + i
    {
        const int j = tid;
        float mf[16];
        #pragma unroll
        for (int d2 = 0; d2 < 7; ++d2) {
            const double2 mv = mpack[d2 * 256 + j];
            mf[2 * d2] = (float)mv.x; mf[2 * d2 + 1] = (float)mv.y;
        }
        mf[14] = (float)cvec[j];   // pairs with x dim14 = irs (general path; 0 here)
        mf[15] = 0.f;
        #pragma unroll
        for (int ks = 0; ks < 2; ++ks) {
            s16x8 h8, l8;
            #pragma unroll
            for (int i = 0; i < 8; ++i) {
                const float f = mf[8 * ks + i];
                const unsigned short h = bf16_rne(f);
                const float r = f - bf16_to_f32(h);     // exact (Sterbenz)
                h8[i] = (short)h;
                l8[i] = (short)bf16_rne(r);
            }
            bhiS[(j >> 5) * 64 + ks * 32 + (j & 31)] = h8;
            bloS[(j >> 5) * 64 + ks * 32 + (j & 31)] = l8;
        }
    }
    if (tid < NC) zbs[tid] = zb[tid];
    if (tid < SS) wbs[tid] = Wb[tid];
    __syncthreads();

    const int gw = blockIdx.x * 4 + w;               // 0..8191
    const float* xw = x + (size_t)gw * 4 * SS * DI;  // this wave's 4 batches

    // ---- general path only: fp32 inv-std per (bi,row) ----
    if (hc) {
        const int bi = lane >> 4, s = lane & 15;
        const float* xr = xw + (bi * SS + s) * DI;
        float xv[DI]; float sum = 0.f;
        #pragma unroll
        for (int d = 0; d < DI; ++d) { xv[d] = xr[d]; sum += xv[d]; }
        const float mu = sum * (1.0f / (float)DI);
        float vs = 0.f;
        #pragma unroll
        for (int d = 0; d < DI; ++d) { const float t = xv[d] - mu; vs += t * t; }
        irsS[w][bi][s] = 1.0f / sqrtf(vs * (1.0f / (float)DI) + 1e-5f);
        __builtin_amdgcn_wave_barrier();
    }

    // ---- scan: 2 batch-pairs, 8 MFMA tiles each; 16 per-reg trackers ----
    const int col = lane & 31;          // (batchInPair<<4) | band
    const int khf = lane >> 5;          // k-half: k = khf*8 + i
    const int jadd = khf << 2;          // +4*hi term of the C row formula

    for (int pr = 0; pr < 2; ++pr) {
        const int bi   = pr * 2 + (col >> 4);
        const int band = col & 15;

        // B operand: x fragment (all 64 lanes active)
        s16x8 xbh, xbl;
        {
            const float* xr = xw + (bi * SS + band) * DI;
            float xv[8];
            if (khf == 0) {
                #pragma unroll
                for (int i = 0; i < 4; ++i) {
                    const v2f p = *(const v2f*)(xr + 2 * i);
                    xv[2 * i] = p.x; xv[2 * i + 1] = p.y;
                }
            } else {
                #pragma unroll
                for (int i = 0; i < 3; ++i) {
                    const v2f p = *(const v2f*)(xr + 8 + 2 * i);
                    xv[2 * i] = p.x; xv[2 * i + 1] = p.y;
                }
                xv[6] = hc ? irsS[w][bi][band] : 0.f;   // dim14: irs (general path)
                xv[7] = 0.f;
            }
            #pragma unroll
            for (int i = 0; i < 8; ++i) {
                const unsigned short h = bf16_rne(xv[i]);
                const float r = xv[i] - bf16_to_f32(h);
                xbh[i] = (short)h;
                xbl[i] = (short)bf16_rne(r);
            }
        }

        // 16 trackers, one per C reg (cell = {t*32 + rowconst}, 8 patterns)
        float tv[16]; int ti[16];
        #pragma unroll
        for (int r = 0; r < 16; ++r) { tv[r] = -INFINITY; ti[r] = 0; }

        f32x16 z16;
        #pragma unroll
        for (int r = 0; r < 16; ++r) z16[r] = 0.f;

        #pragma unroll
        for (int t = 0; t < 8; ++t) {
            const s16x8 ph = bhiS[t * 64 + lane];
            const s16x8 pl = bloS[t * 64 + lane];
            f32x16 acc = __builtin_amdgcn_mfma_f32_32x32x16_bf16(pl, xbh, z16, 0, 0, 0);
            acc = __builtin_amdgcn_mfma_f32_32x32x16_bf16(ph, xbl, acc, 0, 0, 0);
            acc = __builtin_amdgcn_mfma_f32_32x32x16_bf16(ph, xbh, acc, 0, 0, 0);
            #pragma unroll
            for (int r = 0; r < 16; ++r) {
                const float s = acc[r];
                const bool c = s > tv[r];
                tv[r] = c ? s : tv[r];
                ti[r] = c ? t : ti[r];
            }
        }

        // ---- keys: j = t*32 + (r&3) + 8*(r>>2) + 4*hi ----
        unsigned hk[8], lk[8];
        #pragma unroll
        for (int r2 = 0; r2 < 8; ++r2) {
            const int ra = 2 * r2, rb = 2 * r2 + 1;
            const int ja = ti[ra] * 32 + ((ra & 3) + 8 * (ra >> 2)) + jadd;
            const int jb = ti[rb] * 32 + ((rb & 3) + 8 * (rb >> 2)) + jadd;
            const unsigned ka = key32(tv[ra], ja);
            const unsigned kb = key32(tv[rb], jb);
            hk[r2] = ka > kb ? ka : kb;
            lk[r2] = ka > kb ? kb : ka;
        }
        // merge 8 (H,L) -> 1
        #pragma unroll
        for (int st = 4; st > 0; st >>= 1) {
            #pragma unroll
            for (int m = 0; m < 4; ++m) {
                if (m < st) {
                    const unsigned h1 = hk[m], h2 = hk[m + st];
                    const unsigned l1 = lk[m], l2 = lk[m + st];
                    const unsigned mn = h1 < h2 ? h1 : h2;
                    hk[m] = h1 > h2 ? h1 : h2;
                    const unsigned mx = l1 > l2 ? l1 : l2;
                    lk[m] = mn > mx ? mn : mx;
                }
            }
        }
        unsigned kh = hk[0], kl = lk[0];
        {   // merge with lane^32 (other half of this col's patterns)
            const unsigned oh = (unsigned)__shfl_xor((int)kh, 32);
            const unsigned ol = (unsigned)__shfl_xor((int)kl, 32);
            const unsigned mn = kh < oh ? kh : oh;
            kh = kh > oh ? kh : oh;
            const unsigned mx = kl > ol ? kl : ol;
            kl = mn > mx ? mn : mx;
        }
        if (lane < 32) {
            jcandS[w][bi][band][0] = 255 - (int)(kh & 0xFFu);
            jcandS[w][bi][band][1] = 255 - (int)(kl & 0xFFu);
        }
    }
    __builtin_amdgcn_wave_barrier();

    // ---- fp64 rescore: 128 tasks (4 bi x 16 bands x 2 cands) on 64 lanes x 2 ----
    #pragma unroll
    for (int u = 0; u < 2; ++u) {
        const int task = u * 64 + lane;
        const int bi = task >> 5, row = (task >> 1) & 15, ci = task & 1;
        const int j = jcandS[w][bi][row][ci];
        const float* xr = xw + (bi * SS + row) * DI;
        double a = 0.0;
        #pragma unroll
        for (int d2 = 0; d2 < 7; ++d2) {
            const v2f xp = *(const v2f*)(xr + 2 * d2);
            const double2 mv = mpack[d2 * 256 + j];
            a += (double)xp.x * mv.x + (double)xp.y * mv.y;
        }
        if (hc) {   // general path: + irs64 * c_j
            double xv[DI]; double sum = 0.0;
            #pragma unroll
            for (int d = 0; d < DI; ++d) { xv[d] = (double)xr[d]; sum += xv[d]; }
            const double mu = sum * (1.0 / (double)DI);
            double vs = 0.0;
            #pragma unroll
            for (int d = 0; d < DI; ++d) { const double t = xv[d] - mu; vs += t * t; }
            const double irs64 = 1.0 / sqrt(vs * (1.0 / (double)DI) + 1e-5);
            a += irs64 * cvec[j];
        }
        const double oa = __shfl_xor(a, 1);
        const int    oj = __shfl_xor(j, 1);
        const int jwin = (a > oa || (a == oa && j < oj)) ? j : oj;
        if ((lane & 1) == 0) jstarS[w][bi][row] = jwin;
    }
    __builtin_amdgcn_wave_barrier();

    // ---- head: z fp64 (28 lanes = 4 bi x 7 classes), Tf from global (L2) ----
    if (lane < 4 * NC) {
        const int bi = lane / NC, c = lane % NC;
        double zv = zbs[c];
        #pragma unroll
        for (int s = 0; s < SS; ++s)
            zv += (double)wbs[s] * (double)Tf[jstarS[w][bi][s] * NC + c];
        zrowd[w][bi][c] = zv;
    }
    __builtin_amdgcn_wave_barrier();
    if (lane < 4 * NC) {
        const int bi = lane / NC;
        double m = zrowd[w][bi][0];
        #pragma unroll
        for (int c2 = 1; c2 < NC; ++c2) m = fmax(m, zrowd[w][bi][c2]);
        float den = 0.f;
        #pragma unroll
        for (int c2 = 0; c2 < NC; ++c2) den += __expf((float)(zrowd[w][bi][c2] - m));
        const float num = __expf((float)(zrowd[w][bi][lane % NC] - m));
        out[(size_t)gw * 28 + lane] = num / den;
    }
}

extern "C" void kernel_launch(void* const* d_in, const int* in_sizes, int n_in,
                              void* d_out, int out_size, void* d_ws, size_t ws_size,
                              hipStream_t stream) {
    const float* x      = (const float*)d_in[0];
    const float* lookup = (const float*)d_in[1];
    const float* g_st   = (const float*)d_in[2];
    const float* b_st   = (const float*)d_in[3];
    const float* g_sp   = (const float*)d_in[4];
    const float* b_sp   = (const float*)d_in[5];
    const float* g_pp   = (const float*)d_in[6];
    const float* b_pp   = (const float*)d_in[7];
    const float* Wv     = (const float*)d_in[8];
    const float* Wo     = (const float*)d_in[9];
    const float* Wm     = (const float*)d_in[10];
    const float* bm     = (const float*)d_in[11];
    const float* Wb     = (const float*)d_in[12];
    const float* bb     = (const float*)d_in[13];

    double2* mpack = (double2*)((char*)d_ws + WS_MPACK_OFF);
    float*   Tf    = (float*)((char*)d_ws + WS_TF_OFF);
    double*  zbp   = (double*)((char*)d_ws + WS_ZB_OFF);
    double*  cvec  = (double*)((char*)d_ws + WS_CV_OFF);
    int*     hc    = (int*)((char*)d_ws + WS_HC_OFF);

    precompute_kernel<<<1, 256, 0, stream>>>(lookup, g_st, b_st, g_pp, b_pp,
                                             g_sp, b_sp,
                                             Wv, Wo, Wm, bm, Wb, bb,
                                             mpack, Tf, zbp, cvec, hc);
    hopfield_kernel<<<NBLK, 256, 0, stream>>>(x, mpack, cvec, hc, Tf, zbp, Wb,
                                              (float*)d_out);
}

// Round 8
// 146.701 us; speedup vs baseline: 1.1374x; 1.1374x over previous
//
#include <hip/hip_runtime.h>
#include <math.h>

// Problem constants (fixed by setup_inputs)
#define BATCH 32768
#define SS 16          // bands / sequence
#define DI 14          // input dim
#define BQ 256         // stored patterns
#define NC 7           // classes
#define NBLK 2048      // 4 waves/block -> 8192 waves, 4 contiguous batches/wave

// ws layout:
//   mpack : double2[7][256]  (28672 B) m-tilde = g_sp*k - (S/14), packed dim-pairs x pattern
//   Tf    : float[256*7]     ( 7168 B) per-pattern class contribution table
//   zb    : double[7]        (   56 B) bm[c]*sum(Wb) + bb
//   cvec  : double[256]      ( 2048 B) c_j = b_sp . k_j   (all 0 for these inputs)
//   hc    : int              (    4 B) any(b_sp != 0)
#define WS_MPACK_OFF 0
#define WS_TF_OFF    28672
#define WS_ZB_OFF    35840
#define WS_CV_OFF    35896
#define WS_HC_OFF    37944

typedef float  f32x16 __attribute__((ext_vector_type(16)));
typedef short  s16x8  __attribute__((ext_vector_type(8)));
typedef float  v2f    __attribute__((ext_vector_type(2)));

__device__ __forceinline__ unsigned short bf16_rne(float f) {
    unsigned u = __float_as_uint(f);
    unsigned r = u + 0x7FFFu + ((u >> 16) & 1u);
    return (unsigned short)(r >> 16);
}
__device__ __forceinline__ float bf16_to_f32(unsigned short h) {
    return __uint_as_float(((unsigned)h) << 16);
}

// Monotone fp32->u32 order map, top 24 bits kept, low byte = (255-j).
// u32 compare == "score desc, then lowest j" at 2^-16 relative quantization —
// below the bf16-split scan error; fp64 rescore covers both error tiers.
__device__ __forceinline__ unsigned key32(float v, int j) {
    unsigned u = __float_as_uint(v);
    u ^= ((unsigned)((int)u >> 31)) | 0x80000000u;
    return (u & 0xFFFFFF00u) | (unsigned)(255 - j);
}

__global__ __launch_bounds__(256) void precompute_kernel(
    const float* __restrict__ lookup,
    const float* __restrict__ g_st, const float* __restrict__ b_st,
    const float* __restrict__ g_pp, const float* __restrict__ b_pp,
    const float* __restrict__ g_sp, const float* __restrict__ b_sp,
    const float* __restrict__ Wv,  const float* __restrict__ Wo,
    const float* __restrict__ Wm,  const float* __restrict__ bm,
    const float* __restrict__ Wb,  const float* __restrict__ bb,
    double2* __restrict__ mpack, float* __restrict__ Tf, double* __restrict__ zb,
    double* __restrict__ cvec, int* __restrict__ hc)
{
    __shared__ double G1s[256][7];   // (Wo.T @ Wm.T)  : [p][c]
    __shared__ double Gs[14][7];     // Wv.T @ G1      : [d][c]
    const int tid = threadIdx.x;

    // G1[p][c] = sum_o Wo[o,p] * Wm[c,o]
    {
        const int p = tid;
        for (int c = 0; c < NC; ++c) {
            double acc = 0.0;
            for (int o = 0; o < 28; ++o)
                acc += (double)Wo[o * 256 + p] * (double)Wm[c * 28 + o];
            G1s[p][c] = acc;
        }
    }
    __syncthreads();
    // G[d][c] = sum_p Wv[p,d] * G1[p][c]
    if (tid < DI * NC) {
        const int d = tid / NC, c = tid % NC;
        double acc = 0.0;
        for (int p = 0; p < 256; ++p)
            acc += (double)Wv[p * DI + d] * G1s[p][c];
        Gs[d][c] = acc;
    }
    __syncthreads();

    // Per stored pattern j: LayerNorm once (fp64), emit m-tilde, c_j, T row.
    {
        const int j = tid;
        double xr[DI];
        double sum = 0.0;
        for (int d = 0; d < DI; ++d) { xr[d] = (double)lookup[j * DI + d]; sum += xr[d]; }
        const double mu = sum * (1.0 / (double)DI);
        double vs = 0.0;
        for (int d = 0; d < DI; ++d) { const double t = xr[d] - mu; vs += t * t; }
        const double rs = 1.0 / sqrt(vs * (1.0 / (double)DI) + 1e-5);

        double kj[DI], vl[DI];
        for (int d = 0; d < DI; ++d) {
            const double nrm = (xr[d] - mu) * rs;
            kj[d] = nrm * (double)g_st[d] + (double)b_st[d];
            vl[d] = nrm * (double)g_pp[d] + (double)b_pp[d];
        }
        // m_j = g_sp .* k_j ; m~_j = m_j - (sum m_j)/14 ; c_j = b_sp . k_j
        double mv[DI], S = 0.0, cj = 0.0;
        for (int d = 0; d < DI; ++d) {
            mv[d] = kj[d] * (double)g_sp[d];
            S += mv[d];
            cj += (double)b_sp[d] * kj[d];
        }
        const double Sm = S * (1.0 / (double)DI);
        for (int d2 = 0; d2 < DI / 2; ++d2) {
            double2 p; p.x = mv[2 * d2] - Sm; p.y = mv[2 * d2 + 1] - Sm;
            mpack[d2 * 256 + j] = p;
        }
        cvec[j] = cj;

        for (int c = 0; c < NC; ++c) {
            double acc = 0.0;
            for (int d = 0; d < DI; ++d) acc += vl[d] * Gs[d][c];
            Tf[j * NC + c] = (float)acc;
        }
    }
    if (tid < NC) {
        double wbsum = 0.0;
        for (int s = 0; s < SS; ++s) wbsum += (double)Wb[s];
        zb[tid] = (double)bm[tid] * wbsum + (double)bb[0];
    }
    if (tid == 0) {
        int f = 0;
        for (int d = 0; d < DI; ++d) f |= (b_sp[d] != 0.0f) ? 1 : 0;
        *hc = f;
    }
}

// One wave = 4 contiguous batches processed as 2 PAIRS via 32x32x16 MFMA:
// tile = 32 patterns x 32 cols (2 batches x 16 bands), K=16 (DI=14 + irs dim,
// NO padding waste). A = pattern frags (row=lane&31, k=(lane>>5)*8+i),
// B = x frags (col=lane&31, k=(lane>>5)*8+i). C (m74/m101-verified):
// col=lane&31=(batchInPair,band), row=(reg&3)+8*(reg>>2)+4*(lane>>5).
// Per lane: 16 per-reg trackers; cells {j = c mod 32} of size 8 — the exact
// partition proven in R6. In-lane top-2 tree + one lane^32 shfl merge.
// fp64 rescore of top-2 per band unchanged -> identical decisions.
//
// R8 vs R7 (ONLY change): __launch_bounds__(256, 2) — R7's min-waves=4 hint
// capped the allocator at 64 VGPR; the 16-tracker file + f32x16 acc needs
// ~100, so the compiler spilled to scratch (WRITE_SIZE 896KB->62MB). At 2
// waves/EU the cap is 128 VGPR: no spill; LDS 21.5KB still allows multiple
// blocks/CU (VGPR-bound ~16 waves/CU, above R6's measured occupancy).
__global__ __launch_bounds__(256, 2) void hopfield_kernel(
    const float* __restrict__ x,
    const double2* __restrict__ mpack, const double* __restrict__ cvec,
    const int* __restrict__ hcp,
    const float* __restrict__ Tf, const double* __restrict__ zb,
    const float* __restrict__ Wb, float* __restrict__ out)
{
    __shared__ s16x8  bhiS[8 * 64];           // pattern hi frags [tile][lane]  8 KiB
    __shared__ s16x8  bloS[8 * 64];           // pattern lo frags               8 KiB
    __shared__ double zbs[NC];
    __shared__ float  wbs[SS];
    __shared__ int    jcandS[4][4][SS][2];    // [wave][bi][band][cand]
    __shared__ int    jstarS[4][4][SS];
    __shared__ double zrowd[4][4][NC];
    __shared__ float  irsS[4][4][SS];         // general path only (hc != 0)

    const int tid  = threadIdx.x;
    const int lane = tid & 63;
    const int w    = tid >> 6;
    const int hc   = *hcp;

    // ---- stage pattern fragments (hi/lo bf16 splits of fp32(m~)), thread = pattern j ----
    // entry index for (j, khalf): (j>>5)*64 + khalf*32 + (j&31); k = khalf*8 + i
    {
        const int j = tid;
        float mf[16];
        #pragma unroll
        for (int d2 = 0; d2 < 7; ++d2) {
            const double2 mv = mpack[d2 * 256 + j];
            mf[2 * d2] = (float)mv.x; mf[2 * d2 + 1] = (float)mv.y;
        }
        mf[14] = (float)cvec[j];   // pairs with x dim14 = irs (general path; 0 here)
        mf[15] = 0.f;
        #pragma unroll
        for (int ks = 0; ks < 2; ++ks) {
            s16x8 h8, l8;
            #pragma unroll
            for (int i = 0; i < 8; ++i) {
                const float f = mf[8 * ks + i];
                const unsigned short h = bf16_rne(f);
                const float r = f - bf16_to_f32(h);     // exact (Sterbenz)
                h8[i] = (short)h;
                l8[i] = (short)bf16_rne(r);
            }
            bhiS[(j >> 5) * 64 + ks * 32 + (j & 31)] = h8;
            bloS[(j >> 5) * 64 + ks * 32 + (j & 31)] = l8;
        }
    }
    if (tid < NC) zbs[tid] = zb[tid];
    if (tid < SS) wbs[tid] = Wb[tid];
    __syncthreads();

    const int gw = blockIdx.x * 4 + w;               // 0..8191
    const float* xw = x + (size_t)gw * 4 * SS * DI;  // this wave's 4 batches

    // ---- general path only: fp32 inv-std per (bi,row) ----
    if (hc) {
        const int bi = lane >> 4, s = lane & 15;
        const float* xr = xw + (bi * SS + s) * DI;
        float xv[DI]; float sum = 0.f;
        #pragma unroll
        for (int d = 0; d < DI; ++d) { xv[d] = xr[d]; sum += xv[d]; }
        const float mu = sum * (1.0f / (float)DI);
        float vs = 0.f;
        #pragma unroll
        for (int d = 0; d < DI; ++d) { const float t = xv[d] - mu; vs += t * t; }
        irsS[w][bi][s] = 1.0f / sqrtf(vs * (1.0f / (float)DI) + 1e-5f);
        __builtin_amdgcn_wave_barrier();
    }

    // ---- scan: 2 batch-pairs, 8 MFMA tiles each; 16 per-reg trackers ----
    const int col = lane & 31;          // (batchInPair<<4) | band
    const int khf = lane >> 5;          // k-half: k = khf*8 + i
    const int jadd = khf << 2;          // +4*hi term of the C row formula

    for (int pr = 0; pr < 2; ++pr) {
        const int bi   = pr * 2 + (col >> 4);
        const int band = col & 15;

        // B operand: x fragment (all 64 lanes active)
        s16x8 xbh, xbl;
        {
            const float* xr = xw + (bi * SS + band) * DI;
            float xv[8];
            if (khf == 0) {
                #pragma unroll
                for (int i = 0; i < 4; ++i) {
                    const v2f p = *(const v2f*)(xr + 2 * i);
                    xv[2 * i] = p.x; xv[2 * i + 1] = p.y;
                }
            } else {
                #pragma unroll
                for (int i = 0; i < 3; ++i) {
                    const v2f p = *(const v2f*)(xr + 8 + 2 * i);
                    xv[2 * i] = p.x; xv[2 * i + 1] = p.y;
                }
                xv[6] = hc ? irsS[w][bi][band] : 0.f;   // dim14: irs (general path)
                xv[7] = 0.f;
            }
            #pragma unroll
            for (int i = 0; i < 8; ++i) {
                const unsigned short h = bf16_rne(xv[i]);
                const float r = xv[i] - bf16_to_f32(h);
                xbh[i] = (short)h;
                xbl[i] = (short)bf16_rne(r);
            }
        }

        // 16 trackers, one per C reg (cell = {t*32 + rowconst}, 8 patterns)
        float tv[16]; int ti[16];
        #pragma unroll
        for (int r = 0; r < 16; ++r) { tv[r] = -INFINITY; ti[r] = 0; }

        f32x16 z16;
        #pragma unroll
        for (int r = 0; r < 16; ++r) z16[r] = 0.f;

        #pragma unroll
        for (int t = 0; t < 8; ++t) {
            const s16x8 ph = bhiS[t * 64 + lane];
            const s16x8 pl = bloS[t * 64 + lane];
            f32x16 acc = __builtin_amdgcn_mfma_f32_32x32x16_bf16(pl, xbh, z16, 0, 0, 0);
            acc = __builtin_amdgcn_mfma_f32_32x32x16_bf16(ph, xbl, acc, 0, 0, 0);
            acc = __builtin_amdgcn_mfma_f32_32x32x16_bf16(ph, xbh, acc, 0, 0, 0);
            #pragma unroll
            for (int r = 0; r < 16; ++r) {
                const float s = acc[r];
                const bool c = s > tv[r];
                tv[r] = c ? s : tv[r];
                ti[r] = c ? t : ti[r];
            }
        }

        // ---- keys: j = t*32 + (r&3) + 8*(r>>2) + 4*hi ----
        unsigned hk[8], lk[8];
        #pragma unroll
        for (int r2 = 0; r2 < 8; ++r2) {
            const int ra = 2 * r2, rb = 2 * r2 + 1;
            const int ja = ti[ra] * 32 + ((ra & 3) + 8 * (ra >> 2)) + jadd;
            const int jb = ti[rb] * 32 + ((rb & 3) + 8 * (rb >> 2)) + jadd;
            const unsigned ka = key32(tv[ra], ja);
            const unsigned kb = key32(tv[rb], jb);
            hk[r2] = ka > kb ? ka : kb;
            lk[r2] = ka > kb ? kb : ka;
        }
        // merge 8 (H,L) -> 1
        #pragma unroll
        for (int st = 4; st > 0; st >>= 1) {
            #pragma unroll
            for (int m = 0; m < 4; ++m) {
                if (m < st) {
                    const unsigned h1 = hk[m], h2 = hk[m + st];
                    const unsigned l1 = lk[m], l2 = lk[m + st];
                    const unsigned mn = h1 < h2 ? h1 : h2;
                    hk[m] = h1 > h2 ? h1 : h2;
                    const unsigned mx = l1 > l2 ? l1 : l2;
                    lk[m] = mn > mx ? mn : mx;
                }
            }
        }
        unsigned kh = hk[0], kl = lk[0];
        {   // merge with lane^32 (other half of this col's patterns)
            const unsigned oh = (unsigned)__shfl_xor((int)kh, 32);
            const unsigned ol = (unsigned)__shfl_xor((int)kl, 32);
            const unsigned mn = kh < oh ? kh : oh;
            kh = kh > oh ? kh : oh;
            const unsigned mx = kl > ol ? kl : ol;
            kl = mn > mx ? mn : mx;
        }
        if (lane < 32) {
            jcandS[w][bi][band][0] = 255 - (int)(kh & 0xFFu);
            jcandS[w][bi][band][1] = 255 - (int)(kl & 0xFFu);
        }
    }
    __builtin_amdgcn_wave_barrier();

    // ---- fp64 rescore: 128 tasks (4 bi x 16 bands x 2 cands) on 64 lanes x 2 ----
    #pragma unroll
    for (int u = 0; u < 2; ++u) {
        const int task = u * 64 + lane;
        const int bi = task >> 5, row = (task >> 1) & 15, ci = task & 1;
        const int j = jcandS[w][bi][row][ci];
        const float* xr = xw + (bi * SS + row) * DI;
        double a = 0.0;
        #pragma unroll
        for (int d2 = 0; d2 < 7; ++d2) {
            const v2f xp = *(const v2f*)(xr + 2 * d2);
            const double2 mv = mpack[d2 * 256 + j];
            a += (double)xp.x * mv.x + (double)xp.y * mv.y;
        }
        if (hc) {   // general path: + irs64 * c_j
            double xv[DI]; double sum = 0.0;
            #pragma unroll
            for (int d = 0; d < DI; ++d) { xv[d] = (double)xr[d]; sum += xv[d]; }
            const double mu = sum * (1.0 / (double)DI);
            double vs = 0.0;
            #pragma unroll
            for (int d = 0; d < DI; ++d) { const double t = xv[d] - mu; vs += t * t; }
            const double irs64 = 1.0 / sqrt(vs * (1.0 / (double)DI) + 1e-5);
            a += irs64 * cvec[j];
        }
        const double oa = __shfl_xor(a, 1);
        const int    oj = __shfl_xor(j, 1);
        const int jwin = (a > oa || (a == oa && j < oj)) ? j : oj;
        if ((lane & 1) == 0) jstarS[w][bi][row] = jwin;
    }
    __builtin_amdgcn_wave_barrier();

    // ---- head: z fp64 (28 lanes = 4 bi x 7 classes), Tf from global (L2) ----
    if (lane < 4 * NC) {
        const int bi = lane / NC, c = lane % NC;
        double zv = zbs[c];
        #pragma unroll
        for (int s = 0; s < SS; ++s)
            zv += (double)wbs[s] * (double)Tf[jstarS[w][bi][s] * NC + c];
        zrowd[w][bi][c] = zv;
    }
    __builtin_amdgcn_wave_barrier();
    if (lane < 4 * NC) {
        const int bi = lane / NC;
        double m = zrowd[w][bi][0];
        #pragma unroll
        for (int c2 = 1; c2 < NC; ++c2) m = fmax(m, zrowd[w][bi][c2]);
        float den = 0.f;
        #pragma unroll
        for (int c2 = 0; c2 < NC; ++c2) den += __expf((float)(zrowd[w][bi][c2] - m));
        const float num = __expf((float)(zrowd[w][bi][lane % NC] - m));
        out[(size_t)gw * 28 + lane] = num / den;
    }
}

extern "C" void kernel_launch(void* const* d_in, const int* in_sizes, int n_in,
                              void* d_out, int out_size, void* d_ws, size_t ws_size,
                              hipStream_t stream) {
    const float* x      = (const float*)d_in[0];
    const float* lookup = (const float*)d_in[1];
    const float* g_st   = (const float*)d_in[2];
    const float* b_st   = (const float*)d_in[3];
    const float* g_sp   = (const float*)d_in[4];
    const float* b_sp   = (const float*)d_in[5];
    const float* g_pp   = (const float*)d_in[6];
    const float* b_pp   = (const float*)d_in[7];
    const float* Wv     = (const float*)d_in[8];
    const float* Wo     = (const float*)d_in[9];
    const float* Wm     = (const float*)d_in[10];
    const float* bm     = (const float*)d_in[11];
    const float* Wb     = (const float*)d_in[12];
    const float* bb     = (const float*)d_in[13];

    double2* mpack = (double2*)((char*)d_ws + WS_MPACK_OFF);
    float*   Tf    = (float*)((char*)d_ws + WS_TF_OFF);
    double*  zbp   = (double*)((char*)d_ws + WS_ZB_OFF);
    double*  cvec  = (double*)((char*)d_ws + WS_CV_OFF);
    int*     hc    = (int*)((char*)d_ws + WS_HC_OFF);

    precompute_kernel<<<1, 256, 0, stream>>>(lookup, g_st, b_st, g_pp, b_pp,
                                             g_sp, b_sp,
                                             Wv, Wo, Wm, bm, Wb, bb,
                                             mpack, Tf, zbp, cvec, hc);
    hopfield_kernel<<<NBLK, 256, 0, stream>>>(x, mpack, cvec, hc, Tf, zbp, Wb,
                                              (float*)d_out);
}

// Round 9
// 140.041 us; speedup vs baseline: 1.1915x; 1.0476x over previous
//
#include <hip/hip_runtime.h>
#include <math.h>

// Problem constants (fixed by setup_inputs)
#define BATCH 32768
#define SS 16          // bands / sequence
#define DI 14          // input dim
#define BQ 256         // stored patterns
#define NC 7           // classes
#define NBLK 2048      // 4 waves/block -> 8192 waves, 4 contiguous batches/wave

// ws layout:
//   mpack : double2[7][256]  (28672 B) m-tilde = g_sp*k - (S/14), packed dim-pairs x pattern
//   Tf    : float[256*7]     ( 7168 B) per-pattern class contribution table
//   zb    : double[7]        (   56 B) bm[c]*sum(Wb) + bb
//   cvec  : double[256]      ( 2048 B) c_j = b_sp . k_j   (all 0 for these inputs)
//   hc    : int              (    4 B) any(b_sp != 0)
//   bfragH: s16x8[512]       ( 8192 B) pattern hi frags, staged layout (optional)
//   bfragL: s16x8[512]       ( 8192 B) pattern lo frags (optional)
#define WS_MPACK_OFF 0
#define WS_TF_OFF    28672
#define WS_ZB_OFF    35840
#define WS_CV_OFF    35896
#define WS_HC_OFF    37944
#define WS_BH_OFF    37952
#define WS_BL_OFF    46144
#define WS_END_TAB   54336

typedef float  f32x16 __attribute__((ext_vector_type(16)));
typedef short  s16x8  __attribute__((ext_vector_type(8)));
typedef float  v2f    __attribute__((ext_vector_type(2)));

__device__ __forceinline__ unsigned short bf16_rne(float f) {
    unsigned u = __float_as_uint(f);
    unsigned r = u + 0x7FFFu + ((u >> 16) & 1u);
    return (unsigned short)(r >> 16);
}
__device__ __forceinline__ float bf16_to_f32(unsigned short h) {
    return __uint_as_float(((unsigned)h) << 16);
}

// Monotone fp32->u32 order map, top 24 bits kept, low byte = (255-j).
// u32 compare == "score desc, then lowest j" at 2^-16 relative quantization —
// below the bf16-split scan error; fp64 rescore covers both error tiers.
__device__ __forceinline__ unsigned key32(float v, int j) {
    unsigned u = __float_as_uint(v);
    u ^= ((unsigned)((int)u >> 31)) | 0x80000000u;
    return (u & 0xFFFFFF00u) | (unsigned)(255 - j);
}

__global__ __launch_bounds__(256) void precompute_kernel(
    const float* __restrict__ lookup,
    const float* __restrict__ g_st, const float* __restrict__ b_st,
    const float* __restrict__ g_pp, const float* __restrict__ b_pp,
    const float* __restrict__ g_sp, const float* __restrict__ b_sp,
    const float* __restrict__ Wv,  const float* __restrict__ Wo,
    const float* __restrict__ Wm,  const float* __restrict__ bm,
    const float* __restrict__ Wb,  const float* __restrict__ bb,
    double2* __restrict__ mpack, float* __restrict__ Tf, double* __restrict__ zb,
    double* __restrict__ cvec, int* __restrict__ hc,
    s16x8* __restrict__ bfragH, s16x8* __restrict__ bfragL)
{
    __shared__ double G1s[256][7];   // (Wo.T @ Wm.T)  : [p][c]
    __shared__ double Gs[14][7];     // Wv.T @ G1      : [d][c]
    const int tid = threadIdx.x;

    // G1[p][c] = sum_o Wo[o,p] * Wm[c,o]
    {
        const int p = tid;
        for (int c = 0; c < NC; ++c) {
            double acc = 0.0;
            for (int o = 0; o < 28; ++o)
                acc += (double)Wo[o * 256 + p] * (double)Wm[c * 28 + o];
            G1s[p][c] = acc;
        }
    }
    __syncthreads();
    // G[d][c] = sum_p Wv[p,d] * G1[p][c]
    if (tid < DI * NC) {
        const int d = tid / NC, c = tid % NC;
        double acc = 0.0;
        for (int p = 0; p < 256; ++p)
            acc += (double)Wv[p * DI + d] * G1s[p][c];
        Gs[d][c] = acc;
    }
    __syncthreads();

    // Per stored pattern j: LayerNorm once (fp64), emit m-tilde, c_j, T row,
    // and (optionally) the bf16 hi/lo MFMA fragment tables in staged layout.
    {
        const int j = tid;
        double xr[DI];
        double sum = 0.0;
        for (int d = 0; d < DI; ++d) { xr[d] = (double)lookup[j * DI + d]; sum += xr[d]; }
        const double mu = sum * (1.0 / (double)DI);
        double vs = 0.0;
        for (int d = 0; d < DI; ++d) { const double t = xr[d] - mu; vs += t * t; }
        const double rs = 1.0 / sqrt(vs * (1.0 / (double)DI) + 1e-5);

        double kj[DI], vl[DI];
        for (int d = 0; d < DI; ++d) {
            const double nrm = (xr[d] - mu) * rs;
            kj[d] = nrm * (double)g_st[d] + (double)b_st[d];
            vl[d] = nrm * (double)g_pp[d] + (double)b_pp[d];
        }
        // m_j = g_sp .* k_j ; m~_j = m_j - (sum m_j)/14 ; c_j = b_sp . k_j
        double mv[DI], S = 0.0, cj = 0.0;
        for (int d = 0; d < DI; ++d) {
            mv[d] = kj[d] * (double)g_sp[d];
            S += mv[d];
            cj += (double)b_sp[d] * kj[d];
        }
        const double Sm = S * (1.0 / (double)DI);
        for (int d2 = 0; d2 < DI / 2; ++d2) {
            double2 p; p.x = mv[2 * d2] - Sm; p.y = mv[2 * d2 + 1] - Sm;
            mpack[d2 * 256 + j] = p;
        }
        cvec[j] = cj;

        if (bfragH) {
            float mf[16];
            for (int d = 0; d < DI; ++d) mf[d] = (float)(mv[d] - Sm);
            mf[14] = (float)cj;     // pairs with x dim14 = irs (general path; 0 here)
            mf[15] = 0.f;
            for (int ks = 0; ks < 2; ++ks) {
                s16x8 h8, l8;
                for (int i = 0; i < 8; ++i) {
                    const float f = mf[8 * ks + i];
                    const unsigned short h = bf16_rne(f);
                    const float r = f - bf16_to_f32(h);     // exact (Sterbenz)
                    h8[i] = (short)h;
                    l8[i] = (short)bf16_rne(r);
                }
                bfragH[(j >> 5) * 64 + ks * 32 + (j & 31)] = h8;
                bfragL[(j >> 5) * 64 + ks * 32 + (j & 31)] = l8;
            }
        }

        for (int c = 0; c < NC; ++c) {
            double acc = 0.0;
            for (int d = 0; d < DI; ++d) acc += vl[d] * Gs[d][c];
            Tf[j * NC + c] = (float)acc;
        }
    }
    if (tid < NC) {
        double wbsum = 0.0;
        for (int s = 0; s < SS; ++s) wbsum += (double)Wb[s];
        zb[tid] = (double)bm[tid] * wbsum + (double)bb[0];
    }
    if (tid == 0) {
        int f = 0;
        for (int d = 0; d < DI; ++d) f |= (b_sp[d] != 0.0f) ? 1 : 0;
        *hc = f;
    }
}

// One wave = 4 contiguous batches processed as 2 PAIRS via 32x32x16 MFMA
// (R8 structure, proven 45.5us / VGPR 128 / no spill). R9 changes:
//  (1) staging copies precomputed bf16 frag tables (pure 16B copies) instead
//      of re-deriving them from fp64 mpack in every block;
//  (2) pair-0 x rows preloaded into regs BEFORE __syncthreads (HBM latency
//      hides under staging+barrier);
//  (3) pair loop unrolled so pair-1 loads hoist into pair-0 compute.
// Scan/tracker/tournament/rescore/head identical to R8 -> same decisions.
__global__ __launch_bounds__(256, 2) void hopfield_kernel(
    const float* __restrict__ x,
    const double2* __restrict__ mpack, const double* __restrict__ cvec,
    const int* __restrict__ hcp,
    const float* __restrict__ Tf, const double* __restrict__ zb,
    const float* __restrict__ Wb,
    const s16x8* __restrict__ bfH, const s16x8* __restrict__ bfL,
    const int use_tab,
    float* __restrict__ out)
{
    __shared__ s16x8  bhiS[8 * 64];           // pattern hi frags [tile][lane]  8 KiB
    __shared__ s16x8  bloS[8 * 64];           // pattern lo frags               8 KiB
    __shared__ double zbs[NC];
    __shared__ float  wbs[SS];
    __shared__ int    jcandS[4][4][SS][2];    // [wave][bi][band][cand]
    __shared__ int    jstarS[4][4][SS];
    __shared__ double zrowd[4][4][NC];
    __shared__ float  irsS[4][4][SS];         // general path only (hc != 0)

    const int tid  = threadIdx.x;
    const int lane = tid & 63;
    const int w    = tid >> 6;
    const int hc   = *hcp;

    const int col  = lane & 31;         // (batchInPair<<4) | band
    const int khf  = lane >> 5;         // k-half: k = khf*8 + i
    const int jadd = khf << 2;          // +4*hi term of the C row formula
    const int band = col & 15;
    const int biA  = col >> 4;          // pair pr -> bi = pr*2 + biA

    const int gw = blockIdx.x * 4 + w;               // 0..8191
    const float* xw = x + (size_t)gw * 4 * SS * DI;  // this wave's 4 batches

    // ---- preload pair-0 x row (independent of LDS; hides under staging) ----
    float xp0[8];
    {
        const float* xr = xw + (biA * SS + band) * DI;
        if (khf == 0) {
            #pragma unroll
            for (int i = 0; i < 4; ++i) {
                const v2f p = *(const v2f*)(xr + 2 * i);
                xp0[2 * i] = p.x; xp0[2 * i + 1] = p.y;
            }
        } else {
            #pragma unroll
            for (int i = 0; i < 3; ++i) {
                const v2f p = *(const v2f*)(xr + 8 + 2 * i);
                xp0[2 * i] = p.x; xp0[2 * i + 1] = p.y;
            }
            xp0[6] = 0.f; xp0[7] = 0.f;
        }
    }

    // ---- stage pattern fragments ----
    if (use_tab) {
        // pure copy of the precomputed tables (L2-hot, 16KB shared by all blocks)
        #pragma unroll
        for (int i = 0; i < 2; ++i) {
            const int idx = i * 256 + tid;
            bhiS[idx] = bfH[idx];
            bloS[idx] = bfL[idx];
        }
    } else {
        // fallback: derive from fp64 mpack (R8 path)
        const int j = tid;
        float mf[16];
        #pragma unroll
        for (int d2 = 0; d2 < 7; ++d2) {
            const double2 mv = mpack[d2 * 256 + j];
            mf[2 * d2] = (float)mv.x; mf[2 * d2 + 1] = (float)mv.y;
        }
        mf[14] = (float)cvec[j];
        mf[15] = 0.f;
        #pragma unroll
        for (int ks = 0; ks < 2; ++ks) {
            s16x8 h8, l8;
            #pragma unroll
            for (int i = 0; i < 8; ++i) {
                const float f = mf[8 * ks + i];
                const unsigned short h = bf16_rne(f);
                const float r = f - bf16_to_f32(h);
                h8[i] = (short)h;
                l8[i] = (short)bf16_rne(r);
            }
            bhiS[(j >> 5) * 64 + ks * 32 + (j & 31)] = h8;
            bloS[(j >> 5) * 64 + ks * 32 + (j & 31)] = l8;
        }
    }
    if (tid < NC) zbs[tid] = zb[tid];
    if (tid < SS) wbs[tid] = Wb[tid];
    __syncthreads();

    // ---- general path only: fp32 inv-std per (bi,row) ----
    if (hc) {
        const int bi = lane >> 4, s = lane & 15;
        const float* xr = xw + (bi * SS + s) * DI;
        float xv[DI]; float sum = 0.f;
        #pragma unroll
        for (int d = 0; d < DI; ++d) { xv[d] = xr[d]; sum += xv[d]; }
        const float mu = sum * (1.0f / (float)DI);
        float vs = 0.f;
        #pragma unroll
        for (int d = 0; d < DI; ++d) { const float t = xv[d] - mu; vs += t * t; }
        irsS[w][bi][s] = 1.0f / sqrtf(vs * (1.0f / (float)DI) + 1e-5f);
        __builtin_amdgcn_wave_barrier();
        if (khf == 1) xp0[6] = irsS[w][biA][band];   // patch preloaded dim14
    }

    // ---- scan: 2 batch-pairs, 8 MFMA tiles each; 16 per-reg trackers ----
    #pragma unroll
    for (int pr = 0; pr < 2; ++pr) {
        const int bi = pr * 2 + biA;

        // B operand source floats (pair0 preloaded; pair1 loads hoist here)
        float xv[8];
        if (pr == 0) {
            #pragma unroll
            for (int i = 0; i < 8; ++i) xv[i] = xp0[i];
        } else {
            const float* xr = xw + (bi * SS + band) * DI;
            if (khf == 0) {
                #pragma unroll
                for (int i = 0; i < 4; ++i) {
                    const v2f p = *(const v2f*)(xr + 2 * i);
                    xv[2 * i] = p.x; xv[2 * i + 1] = p.y;
                }
            } else {
                #pragma unroll
                for (int i = 0; i < 3; ++i) {
                    const v2f p = *(const v2f*)(xr + 8 + 2 * i);
                    xv[2 * i] = p.x; xv[2 * i + 1] = p.y;
                }
                xv[6] = hc ? irsS[w][bi][band] : 0.f;
                xv[7] = 0.f;
            }
        }

        s16x8 xbh, xbl;
        #pragma unroll
        for (int i = 0; i < 8; ++i) {
            const unsigned short h = bf16_rne(xv[i]);
            const float r = xv[i] - bf16_to_f32(h);
            xbh[i] = (short)h;
            xbl[i] = (short)bf16_rne(r);
        }

        // 16 trackers, one per C reg (cell = {t*32 + rowconst}, 8 patterns)
        float tv[16]; int ti[16];
        #pragma unroll
        for (int r = 0; r < 16; ++r) { tv[r] = -INFINITY; ti[r] = 0; }

        f32x16 z16;
        #pragma unroll
        for (int r = 0; r < 16; ++r) z16[r] = 0.f;

        #pragma unroll
        for (int t = 0; t < 8; ++t) {
            const s16x8 ph = bhiS[t * 64 + lane];
            const s16x8 pl = bloS[t * 64 + lane];
            f32x16 acc = __builtin_amdgcn_mfma_f32_32x32x16_bf16(pl, xbh, z16, 0, 0, 0);
            acc = __builtin_amdgcn_mfma_f32_32x32x16_bf16(ph, xbl, acc, 0, 0, 0);
            acc = __builtin_amdgcn_mfma_f32_32x32x16_bf16(ph, xbh, acc, 0, 0, 0);
            #pragma unroll
            for (int r = 0; r < 16; ++r) {
                const float s = acc[r];
                const bool c = s > tv[r];
                tv[r] = c ? s : tv[r];
                ti[r] = c ? t : ti[r];
            }
        }

        // ---- keys: j = t*32 + (r&3) + 8*(r>>2) + 4*hi ----
        unsigned hk[8], lk[8];
        #pragma unroll
        for (int r2 = 0; r2 < 8; ++r2) {
            const int ra = 2 * r2, rb = 2 * r2 + 1;
            const int ja = ti[ra] * 32 + ((ra & 3) + 8 * (ra >> 2)) + jadd;
            const int jb = ti[rb] * 32 + ((rb & 3) + 8 * (rb >> 2)) + jadd;
            const unsigned ka = key32(tv[ra], ja);
            const unsigned kb = key32(tv[rb], jb);
            hk[r2] = ka > kb ? ka : kb;
            lk[r2] = ka > kb ? kb : ka;
        }
        // merge 8 (H,L) -> 1
        #pragma unroll
        for (int st = 4; st > 0; st >>= 1) {
            #pragma unroll
            for (int m = 0; m < 4; ++m) {
                if (m < st) {
                    const unsigned h1 = hk[m], h2 = hk[m + st];
                    const unsigned l1 = lk[m], l2 = lk[m + st];
                    const unsigned mn = h1 < h2 ? h1 : h2;
                    hk[m] = h1 > h2 ? h1 : h2;
                    const unsigned mx = l1 > l2 ? l1 : l2;
                    lk[m] = mn > mx ? mn : mx;
                }
            }
        }
        unsigned kh = hk[0], kl = lk[0];
        {   // merge with lane^32 (other half of this col's patterns)
            const unsigned oh = (unsigned)__shfl_xor((int)kh, 32);
            const unsigned ol = (unsigned)__shfl_xor((int)kl, 32);
            const unsigned mn = kh < oh ? kh : oh;
            kh = kh > oh ? kh : oh;
            const unsigned mx = kl > ol ? kl : ol;
            kl = mn > mx ? mn : mx;
        }
        if (lane < 32) {
            jcandS[w][bi][band][0] = 255 - (int)(kh & 0xFFu);
            jcandS[w][bi][band][1] = 255 - (int)(kl & 0xFFu);
        }
    }
    __builtin_amdgcn_wave_barrier();

    // ---- fp64 rescore: 128 tasks (4 bi x 16 bands x 2 cands) on 64 lanes x 2 ----
    #pragma unroll
    for (int u = 0; u < 2; ++u) {
        const int task = u * 64 + lane;
        const int bi = task >> 5, row = (task >> 1) & 15, ci = task & 1;
        const int j = jcandS[w][bi][row][ci];
        const float* xr = xw + (bi * SS + row) * DI;
        double a = 0.0;
        #pragma unroll
        for (int d2 = 0; d2 < 7; ++d2) {
            const v2f xp = *(const v2f*)(xr + 2 * d2);
            const double2 mv = mpack[d2 * 256 + j];
            a += (double)xp.x * mv.x + (double)xp.y * mv.y;
        }
        if (hc) {   // general path: + irs64 * c_j
            double xv[DI]; double sum = 0.0;
            #pragma unroll
            for (int d = 0; d < DI; ++d) { xv[d] = (double)xr[d]; sum += xv[d]; }
            const double mu = sum * (1.0 / (double)DI);
            double vs = 0.0;
            #pragma unroll
            for (int d = 0; d < DI; ++d) { const double t = xv[d] - mu; vs += t * t; }
            const double irs64 = 1.0 / sqrt(vs * (1.0 / (double)DI) + 1e-5);
            a += irs64 * cvec[j];
        }
        const double oa = __shfl_xor(a, 1);
        const int    oj = __shfl_xor(j, 1);
        const int jwin = (a > oa || (a == oa && j < oj)) ? j : oj;
        if ((lane & 1) == 0) jstarS[w][bi][row] = jwin;
    }
    __builtin_amdgcn_wave_barrier();

    // ---- head: z fp64 (28 lanes = 4 bi x 7 classes), Tf from global (L2) ----
    if (lane < 4 * NC) {
        const int bi = lane / NC, c = lane % NC;
        double zv = zbs[c];
        #pragma unroll
        for (int s = 0; s < SS; ++s)
            zv += (double)wbs[s] * (double)Tf[jstarS[w][bi][s] * NC + c];
        zrowd[w][bi][c] = zv;
    }
    __builtin_amdgcn_wave_barrier();
    if (lane < 4 * NC) {
        const int bi = lane / NC;
        double m = zrowd[w][bi][0];
        #pragma unroll
        for (int c2 = 1; c2 < NC; ++c2) m = fmax(m, zrowd[w][bi][c2]);
        float den = 0.f;
        #pragma unroll
        for (int c2 = 0; c2 < NC; ++c2) den += __expf((float)(zrowd[w][bi][c2] - m));
        const float num = __expf((float)(zrowd[w][bi][lane % NC] - m));
        out[(size_t)gw * 28 + lane] = num / den;
    }
}

extern "C" void kernel_launch(void* const* d_in, const int* in_sizes, int n_in,
                              void* d_out, int out_size, void* d_ws, size_t ws_size,
                              hipStream_t stream) {
    const float* x      = (const float*)d_in[0];
    const float* lookup = (const float*)d_in[1];
    const float* g_st   = (const float*)d_in[2];
    const float* b_st   = (const float*)d_in[3];
    const float* g_sp   = (const float*)d_in[4];
    const float* b_sp   = (const float*)d_in[5];
    const float* g_pp   = (const float*)d_in[6];
    const float* b_pp   = (const float*)d_in[7];
    const float* Wv     = (const float*)d_in[8];
    const float* Wo     = (const float*)d_in[9];
    const float* Wm     = (const float*)d_in[10];
    const float* bm     = (const float*)d_in[11];
    const float* Wb     = (const float*)d_in[12];
    const float* bb     = (const float*)d_in[13];

    double2* mpack = (double2*)((char*)d_ws + WS_MPACK_OFF);
    float*   Tf    = (float*)((char*)d_ws + WS_TF_OFF);
    double*  zbp   = (double*)((char*)d_ws + WS_ZB_OFF);
    double*  cvec  = (double*)((char*)d_ws + WS_CV_OFF);
    int*     hc    = (int*)((char*)d_ws + WS_HC_OFF);

    const int use_tab = (ws_size >= (size_t)WS_END_TAB) ? 1 : 0;
    s16x8* bfH = use_tab ? (s16x8*)((char*)d_ws + WS_BH_OFF) : (s16x8*)nullptr;
    s16x8* bfL = use_tab ? (s16x8*)((char*)d_ws + WS_BL_OFF) : (s16x8*)nullptr;

    precompute_kernel<<<1, 256, 0, stream>>>(lookup, g_st, b_st, g_pp, b_pp,
                                             g_sp, b_sp,
                                             Wv, Wo, Wm, bm, Wb, bb,
                                             mpack, Tf, zbp, cvec, hc, bfH, bfL);
    hopfield_kernel<<<NBLK, 256, 0, stream>>>(x, mpack, cvec, hc, Tf, zbp, Wb,
                                              bfH, bfL, use_tab,
                                              (float*)d_out);
}

// Round 10
// 133.562 us; speedup vs baseline: 1.2493x; 1.0485x over previous
//
#include <hip/hip_runtime.h>
#include <math.h>

// Problem constants (fixed by setup_inputs)
#define BATCH 32768
#define SS 16          // bands / sequence
#define DI 14          // input dim
#define BQ 256         // stored patterns
#define NC 7           // classes
#define NBLK 2048      // 4 waves/block -> 8192 waves, 4 contiguous batches/wave

#define BIAS 64.0f     // score bias via K-dim 15 (pattern=64, x=1): makes all
                       // scan scores positive so float bits are u32-monotone

// ws layout:
//   mpack : double2[7][256]  (28672 B) m-tilde = g_sp*k - (S/14), packed dim-pairs x pattern
//   Tf    : float[256*7]     ( 7168 B) per-pattern class contribution table
//   zb    : double[7]        (   56 B) bm[c]*sum(Wb) + bb
//   cvec  : double[256]      ( 2048 B) c_j = b_sp . k_j   (all 0 for these inputs)
//   hc    : int              (    4 B) any(b_sp != 0)
//   bfragH: s16x8[512]       ( 8192 B) pattern hi frags, staged layout (optional)
//   bfragL: s16x8[512]       ( 8192 B) pattern lo frags (optional)
#define WS_MPACK_OFF 0
#define WS_TF_OFF    28672
#define WS_ZB_OFF    35840
#define WS_CV_OFF    35896
#define WS_HC_OFF    37944
#define WS_BH_OFF    37952
#define WS_BL_OFF    46144
#define WS_END_TAB   54336

typedef float  f32x16 __attribute__((ext_vector_type(16)));
typedef short  s16x8  __attribute__((ext_vector_type(8)));
typedef float  v2f    __attribute__((ext_vector_type(2)));

__device__ __forceinline__ unsigned short bf16_rne(float f) {
    unsigned u = __float_as_uint(f);
    unsigned r = u + 0x7FFFu + ((u >> 16) & 1u);
    return (unsigned short)(r >> 16);
}
__device__ __forceinline__ float bf16_to_f32(unsigned short h) {
    return __uint_as_float(((unsigned)h) << 16);
}

// Monotone fp32->u32 order map, top 24 bits kept, low byte = (255-j).
// u32 compare == "score desc, then lowest j" at 2^-16 relative quantization —
// below the bf16-split scan error; fp64 rescore covers both error tiers.
__device__ __forceinline__ unsigned key32(float v, int j) {
    unsigned u = __float_as_uint(v);
    u ^= ((unsigned)((int)u >> 31)) | 0x80000000u;
    return (u & 0xFFFFFF00u) | (unsigned)(255 - j);
}

__global__ __launch_bounds__(256) void precompute_kernel(
    const float* __restrict__ lookup,
    const float* __restrict__ g_st, const float* __restrict__ b_st,
    const float* __restrict__ g_pp, const float* __restrict__ b_pp,
    const float* __restrict__ g_sp, const float* __restrict__ b_sp,
    const float* __restrict__ Wv,  const float* __restrict__ Wo,
    const float* __restrict__ Wm,  const float* __restrict__ bm,
    const float* __restrict__ Wb,  const float* __restrict__ bb,
    double2* __restrict__ mpack, float* __restrict__ Tf, double* __restrict__ zb,
    double* __restrict__ cvec, int* __restrict__ hc,
    s16x8* __restrict__ bfragH, s16x8* __restrict__ bfragL)
{
    __shared__ double G1s[256][7];   // (Wo.T @ Wm.T)  : [p][c]
    __shared__ double Gs[14][7];     // Wv.T @ G1      : [d][c]
    const int tid = threadIdx.x;

    // G1[p][c] = sum_o Wo[o,p] * Wm[c,o]
    {
        const int p = tid;
        for (int c = 0; c < NC; ++c) {
            double acc = 0.0;
            for (int o = 0; o < 28; ++o)
                acc += (double)Wo[o * 256 + p] * (double)Wm[c * 28 + o];
            G1s[p][c] = acc;
        }
    }
    __syncthreads();
    // G[d][c] = sum_p Wv[p,d] * G1[p][c]
    if (tid < DI * NC) {
        const int d = tid / NC, c = tid % NC;
        double acc = 0.0;
        for (int p = 0; p < 256; ++p)
            acc += (double)Wv[p * DI + d] * G1s[p][c];
        Gs[d][c] = acc;
    }
    __syncthreads();

    // Per stored pattern j: LayerNorm once (fp64), emit m-tilde, c_j, T row,
    // and (optionally) the bf16 hi/lo MFMA fragment tables in staged layout.
    {
        const int j = tid;
        double xr[DI];
        double sum = 0.0;
        for (int d = 0; d < DI; ++d) { xr[d] = (double)lookup[j * DI + d]; sum += xr[d]; }
        const double mu = sum * (1.0 / (double)DI);
        double vs = 0.0;
        for (int d = 0; d < DI; ++d) { const double t = xr[d] - mu; vs += t * t; }
        const double rs = 1.0 / sqrt(vs * (1.0 / (double)DI) + 1e-5);

        double kj[DI], vl[DI];
        for (int d = 0; d < DI; ++d) {
            const double nrm = (xr[d] - mu) * rs;
            kj[d] = nrm * (double)g_st[d] + (double)b_st[d];
            vl[d] = nrm * (double)g_pp[d] + (double)b_pp[d];
        }
        // m_j = g_sp .* k_j ; m~_j = m_j - (sum m_j)/14 ; c_j = b_sp . k_j
        double mv[DI], S = 0.0, cj = 0.0;
        for (int d = 0; d < DI; ++d) {
            mv[d] = kj[d] * (double)g_sp[d];
            S += mv[d];
            cj += (double)b_sp[d] * kj[d];
        }
        const double Sm = S * (1.0 / (double)DI);
        for (int d2 = 0; d2 < DI / 2; ++d2) {
            double2 p; p.x = mv[2 * d2] - Sm; p.y = mv[2 * d2 + 1] - Sm;
            mpack[d2 * 256 + j] = p;
        }
        cvec[j] = cj;

        if (bfragH) {
            float mf[16];
            for (int d = 0; d < DI; ++d) mf[d] = (float)(mv[d] - Sm);
            mf[14] = (float)cj;     // pairs with x dim14 = irs (general path; 0 here)
            mf[15] = BIAS;          // pairs with x dim15 = 1.0 -> +BIAS on every score
            for (int ks = 0; ks < 2; ++ks) {
                s16x8 h8, l8;
                for (int i = 0; i < 8; ++i) {
                    const float f = mf[8 * ks + i];
                    const unsigned short h = bf16_rne(f);
                    const float r = f - bf16_to_f32(h);     // exact (Sterbenz)
                    h8[i] = (short)h;
                    l8[i] = (short)bf16_rne(r);
                }
                bfragH[(j >> 5) * 64 + ks * 32 + (j & 31)] = h8;
                bfragL[(j >> 5) * 64 + ks * 32 + (j & 31)] = l8;
            }
        }

        for (int c = 0; c < NC; ++c) {
            double acc = 0.0;
            for (int d = 0; d < DI; ++d) acc += vl[d] * Gs[d][c];
            Tf[j * NC + c] = (float)acc;
        }
    }
    if (tid < NC) {
        double wbsum = 0.0;
        for (int s = 0; s < SS; ++s) wbsum += (double)Wb[s];
        zb[tid] = (double)bm[tid] * wbsum + (double)bb[0];
    }
    if (tid == 0) {
        int f = 0;
        for (int d = 0; d < DI; ++d) f |= (b_sp[d] != 0.0f) ? 1 : 0;
        *hc = f;
    }
}

// One wave = 4 contiguous batches processed as 2 PAIRS via 32x32x16 MFMA
// (R8/R9 structure). R10 changes (register-pressure -> occupancy attack):
//  (1) all scan scores biased +BIAS via K-dim15 (pattern=64, x=1, both exact
//      in bf16) -> positive floats -> u32-monotone bit patterns;
//  (2) tracker file is 16 u32 (was 16 float + 16 int): per score
//      tv = umax(tv, (acc_bits & ~7) | t) — same 3 VALU, -16 VGPR, exact
//      index decode t = tv&7. Mantissa-truncation quantization 64*2^-20
//      ~ 6e-5 abs, same order as bf16-split scan error; fp64 rescore of the
//      top-2 candidates (unchanged) still makes every final decision;
//  (3) both pairs' x rows preloaded before staging (HBM latency hidden).
// Rescore/head bit-identical to R8/R9.
__global__ __launch_bounds__(256, 2) void hopfield_kernel(
    const float* __restrict__ x,
    const double2* __restrict__ mpack, const double* __restrict__ cvec,
    const int* __restrict__ hcp,
    const float* __restrict__ Tf, const double* __restrict__ zb,
    const float* __restrict__ Wb,
    const s16x8* __restrict__ bfH, const s16x8* __restrict__ bfL,
    const int use_tab,
    float* __restrict__ out)
{
    __shared__ s16x8  bhiS[8 * 64];           // pattern hi frags [tile][lane]  8 KiB
    __shared__ s16x8  bloS[8 * 64];           // pattern lo frags               8 KiB
    __shared__ double zbs[NC];
    __shared__ float  wbs[SS];
    __shared__ int    jcandS[4][4][SS][2];    // [wave][bi][band][cand]
    __shared__ int    jstarS[4][4][SS];
    __shared__ double zrowd[4][4][NC];
    __shared__ float  irsS[4][4][SS];         // general path only (hc != 0)

    const int tid  = threadIdx.x;
    const int lane = tid & 63;
    const int w    = tid >> 6;
    const int hc   = *hcp;

    const int col  = lane & 31;         // (batchInPair<<4) | band
    const int khf  = lane >> 5;         // k-half: k = khf*8 + i
    const int jadd = khf << 2;          // +4*hi term of the C row formula
    const int band = col & 15;
    const int biA  = col >> 4;          // pair pr -> bi = pr*2 + biA

    const int gw = blockIdx.x * 4 + w;               // 0..8191
    const float* xw = x + (size_t)gw * 4 * SS * DI;  // this wave's 4 batches

    // ---- preload BOTH pairs' x rows (independent of LDS; hides under staging) ----
    float xp[2][8];
    #pragma unroll
    for (int pr = 0; pr < 2; ++pr) {
        const int bi = pr * 2 + biA;
        const float* xr = xw + (bi * SS + band) * DI;
        if (khf == 0) {
            #pragma unroll
            for (int i = 0; i < 4; ++i) {
                const v2f p = *(const v2f*)(xr + 2 * i);
                xp[pr][2 * i] = p.x; xp[pr][2 * i + 1] = p.y;
            }
        } else {
            #pragma unroll
            for (int i = 0; i < 3; ++i) {
                const v2f p = *(const v2f*)(xr + 8 + 2 * i);
                xp[pr][2 * i] = p.x; xp[pr][2 * i + 1] = p.y;
            }
            xp[pr][6] = 0.f;       // dim14: irs (patched below if hc)
            xp[pr][7] = 1.0f;      // dim15: bias partner (pattern[15] = BIAS)
        }
    }

    // ---- stage pattern fragments ----
    if (use_tab) {
        // pure copy of the precomputed tables (L2-hot, 16KB shared by all blocks)
        #pragma unroll
        for (int i = 0; i < 2; ++i) {
            const int idx = i * 256 + tid;
            bhiS[idx] = bfH[idx];
            bloS[idx] = bfL[idx];
        }
    } else {
        // fallback: derive from fp64 mpack (R8 path)
        const int j = tid;
        float mf[16];
        #pragma unroll
        for (int d2 = 0; d2 < 7; ++d2) {
            const double2 mv = mpack[d2 * 256 + j];
            mf[2 * d2] = (float)mv.x; mf[2 * d2 + 1] = (float)mv.y;
        }
        mf[14] = (float)cvec[j];
        mf[15] = BIAS;
        #pragma unroll
        for (int ks = 0; ks < 2; ++ks) {
            s16x8 h8, l8;
            #pragma unroll
            for (int i = 0; i < 8; ++i) {
                const float f = mf[8 * ks + i];
                const unsigned short h = bf16_rne(f);
                const float r = f - bf16_to_f32(h);
                h8[i] = (short)h;
                l8[i] = (short)bf16_rne(r);
            }
            bhiS[(j >> 5) * 64 + ks * 32 + (j & 31)] = h8;
            bloS[(j >> 5) * 64 + ks * 32 + (j & 31)] = l8;
        }
    }
    if (tid < NC) zbs[tid] = zb[tid];
    if (tid < SS) wbs[tid] = Wb[tid];
    __syncthreads();

    // ---- general path only: fp32 inv-std per (bi,row) ----
    if (hc) {
        const int bi = lane >> 4, s = lane & 15;
        const float* xr = xw + (bi * SS + s) * DI;
        float xv[DI]; float sum = 0.f;
        #pragma unroll
        for (int d = 0; d < DI; ++d) { xv[d] = xr[d]; sum += xv[d]; }
        const float mu = sum * (1.0f / (float)DI);
        float vs = 0.f;
        #pragma unroll
        for (int d = 0; d < DI; ++d) { const float t = xv[d] - mu; vs += t * t; }
        irsS[w][bi][s] = 1.0f / sqrtf(vs * (1.0f / (float)DI) + 1e-5f);
        __builtin_amdgcn_wave_barrier();
        if (khf == 1) {
            xp[0][6] = irsS[w][biA][band];       // patch preloaded dim14
            xp[1][6] = irsS[w][2 + biA][band];
        }
    }

    // ---- scan: 2 batch-pairs, 8 MFMA tiles each; 16 u32 trackers ----
    #pragma unroll
    for (int pr = 0; pr < 2; ++pr) {
        const int bi = pr * 2 + biA;

        s16x8 xbh, xbl;
        #pragma unroll
        for (int i = 0; i < 8; ++i) {
            const float f = xp[pr][i];
            const unsigned short h = bf16_rne(f);
            const float r = f - bf16_to_f32(h);
            xbh[i] = (short)h;
            xbl[i] = (short)bf16_rne(r);
        }

        // 16 u32 trackers, one per C reg (cell = {t*32 + rowconst}, 8 patterns).
        // All biased scores positive -> float bits monotone; low 3 mantissa
        // bits carry the tile index t.
        unsigned tv[16];
        #pragma unroll
        for (int r = 0; r < 16; ++r) tv[r] = 0u;

        f32x16 z16;
        #pragma unroll
        for (int r = 0; r < 16; ++r) z16[r] = 0.f;

        #pragma unroll
        for (int t = 0; t < 8; ++t) {
            const s16x8 ph = bhiS[t * 64 + lane];
            const s16x8 pl = bloS[t * 64 + lane];
            f32x16 acc = __builtin_amdgcn_mfma_f32_32x32x16_bf16(pl, xbh, z16, 0, 0, 0);
            acc = __builtin_amdgcn_mfma_f32_32x32x16_bf16(ph, xbl, acc, 0, 0, 0);
            acc = __builtin_amdgcn_mfma_f32_32x32x16_bf16(ph, xbh, acc, 0, 0, 0);
            #pragma unroll
            for (int r = 0; r < 16; ++r) {
                const unsigned tag = (__float_as_uint(acc[r]) & 0xFFFFFFF8u) | (unsigned)t;
                tv[r] = tv[r] > tag ? tv[r] : tag;
            }
        }

        // ---- keys: decode (t, value), j = t*32 + (r&3) + 8*(r>>2) + 4*hi ----
        unsigned hk[8], lk[8];
        #pragma unroll
        for (int r2 = 0; r2 < 8; ++r2) {
            const int ra = 2 * r2, rb = 2 * r2 + 1;
            const int ta = (int)(tv[ra] & 7u), tb = (int)(tv[rb] & 7u);
            const float fa = __uint_as_float(tv[ra] & 0xFFFFFFF8u) - BIAS;
            const float fb = __uint_as_float(tv[rb] & 0xFFFFFFF8u) - BIAS;
            const int ja = ta * 32 + ((ra & 3) + 8 * (ra >> 2)) + jadd;
            const int jb = tb * 32 + ((rb & 3) + 8 * (rb >> 2)) + jadd;
            const unsigned ka = key32(fa, ja);
            const unsigned kb = key32(fb, jb);
            hk[r2] = ka > kb ? ka : kb;
            lk[r2] = ka > kb ? kb : ka;
        }
        // merge 8 (H,L) -> 1
        #pragma unroll
        for (int st = 4; st > 0; st >>= 1) {
            #pragma unroll
            for (int m = 0; m < 4; ++m) {
                if (m < st) {
                    const unsigned h1 = hk[m], h2 = hk[m + st];
                    const unsigned l1 = lk[m], l2 = lk[m + st];
                    const unsigned mn = h1 < h2 ? h1 : h2;
                    hk[m] = h1 > h2 ? h1 : h2;
                    const unsigned mx = l1 > l2 ? l1 : l2;
                    lk[m] = mn > mx ? mn : mx;
                }
            }
        }
        unsigned kh = hk[0], kl = lk[0];
        {   // merge with lane^32 (other half of this col's patterns)
            const unsigned oh = (unsigned)__shfl_xor((int)kh, 32);
            const unsigned ol = (unsigned)__shfl_xor((int)kl, 32);
            const unsigned mn = kh < oh ? kh : oh;
            kh = kh > oh ? kh : oh;
            const unsigned mx = kl > ol ? kl : ol;
            kl = mn > mx ? mn : mx;
        }
        if (lane < 32) {
            jcandS[w][bi][band][0] = 255 - (int)(kh & 0xFFu);
            jcandS[w][bi][band][1] = 255 - (int)(kl & 0xFFu);
        }
    }
    __builtin_amdgcn_wave_barrier();

    // ---- fp64 rescore: 128 tasks (4 bi x 16 bands x 2 cands) on 64 lanes x 2 ----
    #pragma unroll
    for (int u = 0; u < 2; ++u) {
        const int task = u * 64 + lane;
        const int bi = task >> 5, row = (task >> 1) & 15, ci = task & 1;
        const int j = jcandS[w][bi][row][ci];
        const float* xr = xw + (bi * SS + row) * DI;
        double a = 0.0;
        #pragma unroll
        for (int d2 = 0; d2 < 7; ++d2) {
            const v2f xpp = *(const v2f*)(xr + 2 * d2);
            const double2 mv = mpack[d2 * 256 + j];
            a += (double)xpp.x * mv.x + (double)xpp.y * mv.y;
        }
        if (hc) {   // general path: + irs64 * c_j
            double xv[DI]; double sum = 0.0;
            #pragma unroll
            for (int d = 0; d < DI; ++d) { xv[d] = (double)xr[d]; sum += xv[d]; }
            const double mu = sum * (1.0 / (double)DI);
            double vs = 0.0;
            #pragma unroll
            for (int d = 0; d < DI; ++d) { const double t = xv[d] - mu; vs += t * t; }
            const double irs64 = 1.0 / sqrt(vs * (1.0 / (double)DI) + 1e-5);
            a += irs64 * cvec[j];
        }
        const double oa = __shfl_xor(a, 1);
        const int    oj = __shfl_xor(j, 1);
        const int jwin = (a > oa || (a == oa && j < oj)) ? j : oj;
        if ((lane & 1) == 0) jstarS[w][bi][row] = jwin;
    }
    __builtin_amdgcn_wave_barrier();

    // ---- head: z fp64 (28 lanes = 4 bi x 7 classes), Tf from global (L2) ----
    if (lane < 4 * NC) {
        const int bi = lane / NC, c = lane % NC;
        double zv = zbs[c];
        #pragma unroll
        for (int s = 0; s < SS; ++s)
            zv += (double)wbs[s] * (double)Tf[jstarS[w][bi][s] * NC + c];
        zrowd[w][bi][c] = zv;
    }
    __builtin_amdgcn_wave_barrier();
    if (lane < 4 * NC) {
        const int bi = lane / NC;
        double m = zrowd[w][bi][0];
        #pragma unroll
        for (int c2 = 1; c2 < NC; ++c2) m = fmax(m, zrowd[w][bi][c2]);
        float den = 0.f;
        #pragma unroll
        for (int c2 = 0; c2 < NC; ++c2) den += __expf((float)(zrowd[w][bi][c2] - m));
        const float num = __expf((float)(zrowd[w][bi][lane % NC] - m));
        out[(size_t)gw * 28 + lane] = num / den;
    }
}

extern "C" void kernel_launch(void* const* d_in, const int* in_sizes, int n_in,
                              void* d_out, int out_size, void* d_ws, size_t ws_size,
                              hipStream_t stream) {
    const float* x      = (const float*)d_in[0];
    const float* lookup = (const float*)d_in[1];
    const float* g_st   = (const float*)d_in[2];
    const float* b_st   = (const float*)d_in[3];
    const float* g_sp   = (const float*)d_in[4];
    const float* b_sp   = (const float*)d_in[5];
    const float* g_pp   = (const float*)d_in[6];
    const float* b_pp   = (const float*)d_in[7];
    const float* Wv     = (const float*)d_in[8];
    const float* Wo     = (const float*)d_in[9];
    const float* Wm     = (const float*)d_in[10];
    const float* bm     = (const float*)d_in[11];
    const float* Wb     = (const float*)d_in[12];
    const float* bb     = (const float*)d_in[13];

    double2* mpack = (double2*)((char*)d_ws + WS_MPACK_OFF);
    float*   Tf    = (float*)((char*)d_ws + WS_TF_OFF);
    double*  zbp   = (double*)((char*)d_ws + WS_ZB_OFF);
    double*  cvec  = (double*)((char*)d_ws + WS_CV_OFF);
    int*     hc    = (int*)((char*)d_ws + WS_HC_OFF);

    const int use_tab = (ws_size >= (size_t)WS_END_TAB) ? 1 : 0;
    s16x8* bfH = use_tab ? (s16x8*)((char*)d_ws + WS_BH_OFF) : (s16x8*)nullptr;
    s16x8* bfL = use_tab ? (s16x8*)((char*)d_ws + WS_BL_OFF) : (s16x8*)nullptr;

    precompute_kernel<<<1, 256, 0, stream>>>(lookup, g_st, b_st, g_pp, b_pp,
                                             g_sp, b_sp,
                                             Wv, Wo, Wm, bm, Wb, bb,
                                             mpack, Tf, zbp, cvec, hc, bfH, bfL);
    hopfield_kernel<<<NBLK, 256, 0, stream>>>(x, mpack, cvec, hc, Tf, zbp, Wb,
                                              bfH, bfL, use_tab,
                                              (float*)d_out);
}